// Round 2
// baseline (9238.779 us; speedup 1.0000x reference)
//
#include <hip/hip_runtime.h>
#include <hip/hip_bf16.h>

#define NB 8192
#define NH 512
#define NZ 128
#define NIN 128
#define NN 512
#define NRW 16
#define NG 2048   // 4*NH

__device__ __forceinline__ float sigm(float x) { return 1.0f / (1.0f + expf(-x)); }

// C = act( A[M,K] @ W[K,N] + bias + extra[eidx[row]] ) , optionally accumulating into C.
// All dims multiples of {64 (M,N), 16 (K)}; all pointers 16B-aligned.
template<int ACT, int ACC>
__global__ __launch_bounds__(256)
void gemm_f32(const float* __restrict__ A, int lda,
              const float* __restrict__ W, int ldw,
              const float* __restrict__ bias,
              const float* __restrict__ extra, const int* __restrict__ eidx, int lde,
              float* __restrict__ C, int ldc,
              int M, int N, int K)
{
    __shared__ float As[16][64];
    __shared__ float Bs[16][64];
    const int bm = blockIdx.y << 6;
    const int bn = blockIdx.x << 6;
    const int tid = threadIdx.x;
    const int tx = tid & 15, ty = tid >> 4;
    const int ar = tid >> 2, ac = (tid & 3) << 2;   // A tile: 64 rows x 16 k
    const int br = tid >> 4, bc = (tid & 15) << 2;  // B tile: 16 k x 64 cols
    float acc[4][4] = {};
    const float* Ap = A + (size_t)(bm + ar) * lda + ac;
    const float* Wp = W + (size_t)br * ldw + bn + bc;
    for (int kb = 0; kb < K; kb += 16) {
        const float4 av = *(const float4*)(Ap + kb);
        const float4 bv = *(const float4*)(Wp + (size_t)kb * ldw);
        __syncthreads();
        As[ac + 0][ar] = av.x; As[ac + 1][ar] = av.y;
        As[ac + 2][ar] = av.z; As[ac + 3][ar] = av.w;
        *(float4*)(&Bs[br][bc]) = bv;
        __syncthreads();
#pragma unroll
        for (int kk = 0; kk < 16; ++kk) {
            const float4 a4 = *(const float4*)(&As[kk][ty << 2]);
            const float4 b4 = *(const float4*)(&Bs[kk][tx << 2]);
            const float aa[4] = {a4.x, a4.y, a4.z, a4.w};
            const float bb[4] = {b4.x, b4.y, b4.z, b4.w};
#pragma unroll
            for (int i = 0; i < 4; ++i)
#pragma unroll
                for (int j = 0; j < 4; ++j)
                    acc[i][j] = fmaf(aa[i], bb[j], acc[i][j]);
        }
    }
    const int row0 = bm + (ty << 2);
    const int col0 = bn + (tx << 2);
    float4 bi4 = make_float4(0.f, 0.f, 0.f, 0.f);
    if (bias) bi4 = *(const float4*)(bias + col0);
#pragma unroll
    for (int i = 0; i < 4; ++i) {
        const int row = row0 + i;
        float4 ex4 = make_float4(0.f, 0.f, 0.f, 0.f);
        if (extra) {
            const int e = eidx ? eidx[row] : row;
            ex4 = *(const float4*)(extra + (size_t)e * lde + col0);
        }
        float v0 = acc[i][0] + bi4.x + ex4.x;
        float v1 = acc[i][1] + bi4.y + ex4.y;
        float v2 = acc[i][2] + bi4.z + ex4.z;
        float v3 = acc[i][3] + bi4.w + ex4.w;
        float* cp = C + (size_t)row * ldc + col0;
        if (ACC) {
            const float4 old = *(const float4*)cp;
            v0 += old.x; v1 += old.y; v2 += old.z; v3 += old.w;
        }
        if (ACT == 1) { v0 = tanhf(v0); v1 = tanhf(v1); v2 = tanhf(v2); v3 = tanhf(v3); }
        *(float4*)cp = make_float4(v0, v1, v2, v3);
    }
}

// Pointwise LSTM cell update: reads gates[B, 4H], updates h,c in place.
__global__ __launch_bounds__(256)
void lstm_pw(const float* __restrict__ gates, float* __restrict__ h, float* __restrict__ c)
{
    const size_t idx = (size_t)blockIdx.x * 256 + threadIdx.x;  // < NB*NH
    const int b = (int)(idx >> 9);
    const int j = (int)(idx & 511);
    const float* gr = gates + (size_t)b * NG;
    const float ig = gr[j];
    const float gg = gr[512 + j];
    const float fg = gr[1024 + j];
    const float og = gr[1536 + j];
    const float cx = c[idx];
    const float cy = cx * sigm(fg + 1.0f) + sigm(ig) * tanhf(gg);
    const float hy = sigm(og) * tanhf(cy);
    c[idx] = cy;
    h[idx] = hy;
}

// Per row b: argmax_j( logits[b,j] + gumbel(u[t,b,j]) ); write one-hot f32 row into out0
// and the winning index into kidx[t*NB + b].
__global__ __launch_bounds__(256)
void argmax_onehot(const float* __restrict__ logits, const float* __restrict__ gu,
                   float* __restrict__ out0, int* __restrict__ kidx, int t)
{
    const int b = blockIdx.x;
    const int tid = threadIdx.x;
    const float* lrow = logits + (size_t)b * NN;
    const float* urow = gu + ((size_t)t * NB + b) * NN;
    float best = -INFINITY;
    int bi = 0x7fffffff;
#pragma unroll
    for (int q = 0; q < 2; ++q) {
        const int j = tid + q * 256;
        const float u = urow[j];
        const float g = -logf(-logf(u + 1e-20f) + 1e-20f);
        const float v = lrow[j] + g;
        if (v > best || (v == best && j < bi)) { best = v; bi = j; }
    }
#pragma unroll
    for (int off = 32; off > 0; off >>= 1) {
        const float ov = __shfl_down(best, off);
        const int oi = __shfl_down(bi, off);
        if (ov > best || (ov == best && oi < bi)) { best = ov; bi = oi; }
    }
    __shared__ float sv[4];
    __shared__ int si[4];
    const int lane = tid & 63, w = tid >> 6;
    if (lane == 0) { sv[w] = best; si[w] = bi; }
    __syncthreads();
    if (tid == 0) {
        for (int q = 1; q < 4; ++q)
            if (sv[q] > best || (sv[q] == best && si[q] < bi)) { best = sv[q]; bi = si[q]; }
        si[0] = bi;
        kidx[(size_t)t * NB + b] = bi;
    }
    __syncthreads();
    const int win = si[0];
    float* orow = out0 + ((size_t)b * NRW + t) * NN;
#pragma unroll
    for (int q = 0; q < 2; ++q) {
        const int j = tid + q * 256;
        orow[j] = (j == win) ? 1.0f : 0.0f;
    }
}

// out1[b*RW + t] = dot(h[b,:], W_outl) + b_outl, one wave per row.
__global__ __launch_bounds__(256)
void rowdot(const float* __restrict__ h, const float* __restrict__ Woutl,
            const float* __restrict__ boutl, float* __restrict__ out1, int t)
{
    const int w = threadIdx.x >> 6;
    const int lane = threadIdx.x & 63;
    const int b = blockIdx.x * 4 + w;
    const float* hr = h + (size_t)b * NH;
    float s = 0.f;
#pragma unroll
    for (int q = 0; q < 8; ++q) s = fmaf(hr[lane + q * 64], Woutl[lane + q * 64], s);
#pragma unroll
    for (int off = 32; off > 0; off >>= 1) s += __shfl_down(s, off);
    if (lane == 0) out1[(size_t)b * NRW + t] = s + boutl[0];
}

extern "C" void kernel_launch(void* const* d_in, const int* in_sizes, int n_in,
                              void* d_out, int out_size, void* d_ws, size_t ws_size,
                              hipStream_t stream)
{
    const float* latent  = (const float*)d_in[0];
    const float* inputs  = (const float*)d_in[1];
    const float* gu      = (const float*)d_in[2];
    const float* W_int   = (const float*)d_in[3];
    const float* b_int   = (const float*)d_in[4];
    const float* W_intl  = (const float*)d_in[5];
    const float* b_intl  = (const float*)d_in[6];
    const float* W_hup   = (const float*)d_in[7];
    const float* b_hup   = (const float*)d_in[8];
    const float* W_cup   = (const float*)d_in[9];
    const float* b_cup   = (const float*)d_in[10];
    const float* W_hupl  = (const float*)d_in[11];
    const float* b_hupl  = (const float*)d_in[12];
    const float* W_cupl  = (const float*)d_in[13];
    const float* b_cupl  = (const float*)d_in[14];
    const float* W_lstm  = (const float*)d_in[15];
    const float* b_lstm  = (const float*)d_in[16];
    const float* W_up    = (const float*)d_in[17];
    const float* b_up    = (const float*)d_in[18];
    const float* W_down  = (const float*)d_in[19];
    const float* W_downl = (const float*)d_in[20];
    const float* W_outl  = (const float*)d_in[21];
    const float* b_outl  = (const float*)d_in[22];

    float* out0 = (float*)d_out;                       // [B, RW, N]
    float* out1 = out0 + (size_t)NB * NRW * NN;        // [B, RW, 1]

    float* ws     = (float*)d_ws;
    float* inter  = ws;                       // NB*NH
    float* h      = inter + (size_t)NB * NH;  // NB*NH
    float* c      = h + (size_t)NB * NH;      // NB*NH
    float* logits = c + (size_t)NB * NH;      // NB*NN
    float* gates  = logits + (size_t)NB * NN; // NB*NG
    float* gdown  = gates + (size_t)NB * NG;  // NN*NG
    float* gdownl = gdown + (size_t)NN * NG;  // NN*NG
    int*   kidx   = (int*)(gdownl + (size_t)NN * NG); // NRW*NB ints

    const dim3 blk(256);
    const dim3 g_pre(NG / 64, NN / 64);      // 32 x 8
    const dim3 g_h(NH / 64, NB / 64);        // 8 x 128
    const dim3 g_gates(NG / 64, NB / 64);    // 32 x 128

    // Precompute G_down = W_down @ W_lstm[:128,:], G_downl = W_downl @ W_lstm[:128,:]
    gemm_f32<0, 0><<<g_pre, blk, 0, stream>>>(W_down, NIN, W_lstm, NG, nullptr,
                                              nullptr, nullptr, 0, gdown, NG, NN, NG, NIN);
    gemm_f32<0, 0><<<g_pre, blk, 0, stream>>>(W_downl, NIN, W_lstm, NG, nullptr,
                                              nullptr, nullptr, 0, gdownl, NG, NN, NG, NIN);

    // inter = tanh(latent @ W_int + b_int); hx, cx
    gemm_f32<1, 0><<<g_h, blk, 0, stream>>>(latent, NZ, W_int, NH, b_int,
                                            nullptr, nullptr, 0, inter, NH, NB, NH, NZ);
    gemm_f32<1, 0><<<g_h, blk, 0, stream>>>(inter, NH, W_hup, NH, b_hup,
                                            nullptr, nullptr, 0, h, NH, NB, NH, NH);
    gemm_f32<1, 0><<<g_h, blk, 0, stream>>>(inter, NH, W_cup, NH, b_cup,
                                            nullptr, nullptr, 0, c, NH, NB, NH, NH);

    // ---- Loop 1 ----
    for (int t = 0; t < NRW; ++t) {
        if (t == 0) {
            // gates = h @ W_lstm[128:,:] + b_lstm ; then gates += inputs @ W_lstm[:128,:]
            gemm_f32<0, 0><<<g_gates, blk, 0, stream>>>(h, NH, W_lstm + (size_t)NIN * NG, NG,
                                                        b_lstm, nullptr, nullptr, 0,
                                                        gates, NG, NB, NG, NH);
            gemm_f32<0, 1><<<g_gates, blk, 0, stream>>>(inputs, NIN, W_lstm, NG, nullptr,
                                                        nullptr, nullptr, 0,
                                                        gates, NG, NB, NG, NIN);
        } else {
            gemm_f32<0, 0><<<g_gates, blk, 0, stream>>>(h, NH, W_lstm + (size_t)NIN * NG, NG,
                                                        b_lstm, gdown, kidx + (size_t)(t - 1) * NB, NG,
                                                        gates, NG, NB, NG, NH);
        }
        lstm_pw<<<dim3(NB * NH / 256), blk, 0, stream>>>(gates, h, c);
        gemm_f32<0, 0><<<g_h, blk, 0, stream>>>(h, NH, W_up, NH, b_up,
                                                nullptr, nullptr, 0, logits, NN, NB, NN, NH);
        argmax_onehot<<<dim3(NB), blk, 0, stream>>>(logits, gu, out0, kidx, t);
    }

    // ---- Loop 2 init (reuse inter/h/c buffers) ----
    gemm_f32<1, 0><<<g_h, blk, 0, stream>>>(latent, NZ, W_intl, NH, b_intl,
                                            nullptr, nullptr, 0, inter, NH, NB, NH, NZ);
    gemm_f32<1, 0><<<g_h, blk, 0, stream>>>(inter, NH, W_hupl, NH, b_hupl,
                                            nullptr, nullptr, 0, h, NH, NB, NH, NH);
    gemm_f32<1, 0><<<g_h, blk, 0, stream>>>(inter, NH, W_cupl, NH, b_cupl,
                                            nullptr, nullptr, 0, c, NH, NB, NH, NH);

    // ---- Loop 2 ----
    for (int t = 0; t < NRW; ++t) {
        gemm_f32<0, 0><<<g_gates, blk, 0, stream>>>(h, NH, W_lstm + (size_t)NIN * NG, NG,
                                                    b_lstm, gdownl, kidx + (size_t)t * NB, NG,
                                                    gates, NG, NB, NG, NH);
        lstm_pw<<<dim3(NB * NH / 256), blk, 0, stream>>>(gates, h, c);
        rowdot<<<dim3(NB / 4), blk, 0, stream>>>(h, W_outl, b_outl, out1, t);
    }
}